// Round 1
// baseline (862.841 us; speedup 1.0000x reference)
//
#include <hip/hip_runtime.h>
#include <stdint.h>

// Problem constants (fixed by setup_inputs): B=2, C=32, H=W=D=96, N=30000
#define HWD 884736ull          // 96*96*96
#define NVERT_TOT 60000        // B*N flattened
#define KPAD 1024              // 32 channels * 32 (27 taps padded to 32)

typedef __attribute__((ext_vector_type(8))) __bf16 bf16x8;
typedef __attribute__((ext_vector_type(4))) float f32x4;
typedef __attribute__((ext_vector_type(4))) unsigned int uint4v;

__device__ __forceinline__ unsigned short f2bf(float f) {
    union { float f; unsigned int u; } v; v.f = f;
    unsigned int u = v.u;
    return (unsigned short)((u + 0x7FFFu + ((u >> 16) & 1u)) >> 16);  // RNE
}

// Per-axis: replicate reference clamp/floor math for shifts {-1,0,1}, then fold
// into 4-wide window weights. Window start ws = clamp(x0_center-1, 0, 92);
// all clamped tap indices provably lie in [ws, ws+3] (1-ulp floor flips near
// integers land outside only with ~0 weight, so the d0/d1 clamp is safe).
__device__ __forceinline__ void axis_setup(float coord, float sc, int& wstart, float w[3][4]) {
    int i0[3], i1[3];
    float fr[3];
#pragma unroll
    for (int a = 0; a < 3; ++a) {
        float g = coord + (float)(a - 1) * sc;
        float ix = (g + 1.0f) * 0.5f * 95.0f;
        ix = fminf(fmaxf(ix, 0.0f), 95.0f);
        float fl = floorf(ix);
        int x0 = (int)fl;
        i0[a] = x0;
        i1[a] = min(x0 + 1, 95);
        fr[a] = ix - fl;
    }
    int ws = min(max(i0[1] - 1, 0), 92);
    wstart = ws;
#pragma unroll
    for (int a = 0; a < 3; ++a) {
        int d0 = min(max(i0[a] - ws, 0), 3);
        int d1 = min(max(i1[a] - ws, 0), 3);
        float f1 = fr[a], f0 = 1.0f - f1;
#pragma unroll
        for (int j = 0; j < 4; ++j)
            w[a][j] = (d0 == j ? f0 : 0.0f) + (d1 == j ? f1 : 0.0f);
    }
}

// Pack conv_w (32,32,1,27) fp32 -> bf16 B-fragments for mfma_f32_16x16x32_bf16.
// K index = c*32 + kk (kk<27 real, else 0). Layout Wp[s][t][lane][8]:
// B[k = s*32 + (lane>>4)*8 + j][o = t*16 + (lane&15)]
__global__ __launch_bounds__(256) void prep_kernel(const float* __restrict__ cw,
                                                   unsigned short* __restrict__ Wp) {
    int gid = blockIdx.x * 256 + threadIdx.x;  // 0..32767
    int j = gid & 7;
    int l = (gid >> 3) & 63;
    int t = (gid >> 9) & 1;
    int s = gid >> 10;
    int kk = ((l >> 4) & 3) * 8 + j;
    int o = t * 16 + (l & 15);
    float v = 0.0f;
    if (kk < 27) v = cw[(size_t)o * 864 + s * 27 + kk];
    Wp[gid] = f2bf(v);
}

// One thread per (vertex, channel): gather 4x4x4 window (16 rows x 4 floats),
// separable x->y->z contraction to 27 taps, write bf16 feats row (32 padded).
__global__ __launch_bounds__(256) void sample_kernel(const float* __restrict__ vox,
                                                     const float* __restrict__ verts,
                                                     unsigned short* __restrict__ F,
                                                     int vbase, int nverts) {
    int gid = blockIdx.x * 256 + threadIdx.x;
    int c = gid & 31;
    int vl = gid >> 5;
    if (vl >= nverts) return;
    int vg = vbase + vl;
    const float* vp = verts + (size_t)vg * 3;
    float vx = vp[0], vy = vp[1], vz = vp[2];
    const float sc = 2.0f / 95.0f;
    int wsx, wsy, wsz;
    float wx[3][4], wy[3][4], wz[3][4];
    axis_setup(vx, sc, wsx, wx);  // x -> D axis (stride 1)
    axis_setup(vy, sc, wsy, wy);  // y -> W axis (stride 96)
    axis_setup(vz, sc, wsz, wz);  // z -> H axis (stride 96*96)
    int bb = (vg >= 30000) ? 1 : 0;
    const float* vb = vox + (size_t)(bb * 32 + c) * HWD;

    float f[27];
#pragma unroll
    for (int k = 0; k < 27; ++k) f[k] = 0.0f;

#pragma unroll
    for (int tz = 0; tz < 4; ++tz) {
        float rx[4][3];
#pragma unroll
        for (int ty = 0; ty < 4; ++ty) {
            const float* row = vb + ((size_t)(wsz + tz) * 96 + (size_t)(wsy + ty)) * 96 + wsx;
            float b0 = row[0], b1 = row[1], b2 = row[2], b3 = row[3];
#pragma unroll
            for (int a = 0; a < 3; ++a)
                rx[ty][a] = b0 * wx[a][0] + b1 * wx[a][1] + b2 * wx[a][2] + b3 * wx[a][3];
        }
        float ry[3][3];
#pragma unroll
        for (int b = 0; b < 3; ++b)
#pragma unroll
            for (int a = 0; a < 3; ++a)
                ry[b][a] = rx[0][a] * wy[b][0] + rx[1][a] * wy[b][1] +
                           rx[2][a] * wy[b][2] + rx[3][a] * wy[b][3];
#pragma unroll
        for (int g = 0; g < 3; ++g)
#pragma unroll
            for (int b = 0; b < 3; ++b)
#pragma unroll
                for (int a = 0; a < 3; ++a)
                    f[9 * a + 3 * b + g] += wz[g][tz] * ry[b][a];
    }

    unsigned int pk[16];
#pragma unroll
    for (int i = 0; i < 16; ++i) {
        float lo = (2 * i < 27) ? f[2 * i] : 0.0f;
        float hi = (2 * i + 1 < 27) ? f[2 * i + 1] : 0.0f;
        pk[i] = (unsigned int)f2bf(lo) | ((unsigned int)f2bf(hi) << 16);
    }
    uint4v* dst = (uint4v*)(F + ((size_t)vl * KPAD + c * 32));
    uint4v s0 = {pk[0], pk[1], pk[2], pk[3]};
    uint4v s1 = {pk[4], pk[5], pk[6], pk[7]};
    uint4v s2 = {pk[8], pk[9], pk[10], pk[11]};
    uint4v s3 = {pk[12], pk[13], pk[14], pk[15]};
    dst[0] = s0; dst[1] = s1; dst[2] = s2; dst[3] = s3;
}

// out[v,32] = F[v,1024]_bf16 x Wp + bias. One wave per 16-row m-tile, both
// n-tiles (o 0..15, 16..31) accumulated in the same wave.
__global__ __launch_bounds__(256) void gemm_kernel(const unsigned short* __restrict__ F,
                                                   const unsigned short* __restrict__ Wp,
                                                   const float* __restrict__ bias,
                                                   float* __restrict__ out,
                                                   int vbase, int mcount) {
    int wid = (int)blockIdx.x * 4 + ((int)threadIdx.x >> 6);
    int lane = threadIdx.x & 63;
    if (wid * 16 >= mcount) return;
    int v0 = wid * 16;
    int mrow = lane & 15, quad = lane >> 4;
    const bf16x8* arow = (const bf16x8*)(F + (size_t)(v0 + mrow) * KPAD + quad * 8);
    const bf16x8* wp = (const bf16x8*)Wp;
    f32x4 acc0 = {0.f, 0.f, 0.f, 0.f};
    f32x4 acc1 = {0.f, 0.f, 0.f, 0.f};
#pragma unroll 4
    for (int s = 0; s < 32; ++s) {
        bf16x8 a = arow[s * 4];
        bf16x8 b0 = wp[(s * 2 + 0) * 64 + lane];
        bf16x8 b1 = wp[(s * 2 + 1) * 64 + lane];
        acc0 = __builtin_amdgcn_mfma_f32_16x16x32_bf16(a, b0, acc0, 0, 0, 0);
        acc1 = __builtin_amdgcn_mfma_f32_16x16x32_bf16(a, b1, acc1, 0, 0, 0);
    }
    float bs0 = bias[mrow];
    float bs1 = bias[16 + mrow];
#pragma unroll
    for (int r = 0; r < 4; ++r) {
        int v = v0 + quad * 4 + r;
        if (v < mcount) {
            float* o = out + (size_t)(vbase + v) * 32;
            o[mrow] = acc0[r] + bs0;
            o[16 + mrow] = acc1[r] + bs1;
        }
    }
}

extern "C" void kernel_launch(void* const* d_in, const int* in_sizes, int n_in,
                              void* d_out, int out_size, void* d_ws, size_t ws_size,
                              hipStream_t stream) {
    const float* vox = (const float*)d_in[0];
    const float* verts = (const float*)d_in[1];
    const float* cw = (const float*)d_in[2];
    const float* cb = (const float*)d_in[3];
    float* out = (float*)d_out;

    unsigned short* Wp = (unsigned short*)d_ws;
    const size_t WPB = 65536;  // 32*2*64*8 bf16
    unsigned short* F = (unsigned short*)((char*)d_ws + WPB);

    size_t avail = ws_size > WPB ? ws_size - WPB : 0;
    auto need = [](int chunk) { return (size_t)(chunk + 16) * KPAD * 2; };
    int nch;
    if (avail >= need(NVERT_TOT)) nch = 1;
    else if (avail >= need(NVERT_TOT / 4)) nch = 4;
    else nch = 20;
    int chunk = NVERT_TOT / nch;  // 60000, 15000, or 3000 (all divide exactly)

    hipLaunchKernelGGL(prep_kernel, dim3(128), dim3(256), 0, stream, cw, Wp);
    for (int ch = 0; ch < nch; ++ch) {
        int vb = ch * chunk;
        hipLaunchKernelGGL(sample_kernel, dim3(chunk * 32 / 256), dim3(256), 0, stream,
                           vox, verts, F, vb, chunk);
        int mtiles = (chunk + 15) / 16;
        hipLaunchKernelGGL(gemm_kernel, dim3((mtiles + 3) / 4), dim3(256), 0, stream,
                           F, Wp, cb, out, vb, chunk);
    }
}

// Round 2
// 418.067 us; speedup vs baseline: 2.0639x; 2.0639x over previous
//
#include <hip/hip_runtime.h>
#include <stdint.h>

// Problem constants (fixed by setup_inputs): B=2, C=32, H=W=D=96, N=30000
#define HWD 884736ull          // 96*96*96
#define NV 30000               // vertices per batch
#define AST 1032               // LDS A-tile row stride (shorts): 2064B, /4=516, %32=4 -> 2-way only (free)

typedef __attribute__((ext_vector_type(8))) __bf16 bf16x8;
typedef __attribute__((ext_vector_type(4))) float f32x4;
typedef __attribute__((ext_vector_type(4))) unsigned int uint4v;

__device__ __forceinline__ unsigned short f2bf(float f) {
    union { float f; unsigned int u; } v; v.f = f;
    unsigned int u = v.u;
    return (unsigned short)((u + 0x7FFFu + ((u >> 16) & 1u)) >> 16);  // RNE
}

__device__ __forceinline__ float bf2f(unsigned short s) {
    union { unsigned int u; float f; } v;
    v.u = ((unsigned int)s) << 16;
    return v.f;
}

// Per-axis: replicate reference clamp/floor math for shifts {-1,0,1}, then fold
// into 4-wide window weights. Window start ws = clamp(x0_center-1, 0, 92).
__device__ __forceinline__ void axis_setup(float coord, float sc, int& wstart, float w[3][4]) {
    int i0[3], i1[3];
    float fr[3];
#pragma unroll
    for (int a = 0; a < 3; ++a) {
        float g = coord + (float)(a - 1) * sc;
        float ix = (g + 1.0f) * 0.5f * 95.0f;
        ix = fminf(fmaxf(ix, 0.0f), 95.0f);
        float fl = floorf(ix);
        int x0 = (int)fl;
        i0[a] = x0;
        i1[a] = min(x0 + 1, 95);
        fr[a] = ix - fl;
    }
    int ws = min(max(i0[1] - 1, 0), 92);
    wstart = ws;
#pragma unroll
    for (int a = 0; a < 3; ++a) {
        int d0 = min(max(i0[a] - ws, 0), 3);
        int d1 = min(max(i1[a] - ws, 0), 3);
        float f1 = fr[a], f0 = 1.0f - f1;
#pragma unroll
        for (int j = 0; j < 4; ++j)
            w[a][j] = (d0 == j ? f0 : 0.0f) + (d1 == j ? f1 : 0.0f);
    }
}

// Pack conv_w (32,32,1,27) fp32 -> bf16 B-fragments for mfma_f32_16x16x32_bf16.
// Layout (verified round 1): element j of wp[(s*2+t)*64 + lane] is
// B[k = s*32 + (lane>>4)*8 + j][o = t*16 + (lane&15)]
__global__ __launch_bounds__(256) void prep_kernel(const float* __restrict__ cw,
                                                   unsigned short* __restrict__ Wp) {
    int gid = blockIdx.x * 256 + threadIdx.x;  // 0..32767
    int j = gid & 7;
    int l = (gid >> 3) & 63;
    int t = (gid >> 9) & 1;
    int s = gid >> 10;
    int kk = ((l >> 4) & 3) * 8 + j;
    int o = t * 16 + (l & 15);
    float v = 0.0f;
    if (kk < 27) v = cw[(size_t)o * 864 + s * 27 + kk];
    Wp[gid] = f2bf(v);
}

// (B,C,H,W,D) fp32 -> (B,H,W,D,C) bf16. One block per (b,z,y) row: 96 x * 32 c.
// Reads: float4 per lane from per-channel plane rows (L1 absorbs the 4x line split).
// Writes: consecutive c per lane -> 64B contiguous segments, fully coalesced.
__global__ __launch_bounds__(256) void transpose_kernel(const float* __restrict__ vox,
                                                        unsigned short* __restrict__ voxT) {
    int blk = blockIdx.x;            // 0..18431 encodes (b, z, y)
    int tid = threadIdx.x;
    int b = blk / 9216;
    int zy = blk % 9216;
    const float* src = vox + (size_t)b * 32 * HWD + (size_t)zy * 96;
    unsigned short* dst = voxT + (size_t)blk * 3072;
#pragma unroll
    for (int i = 0; i < 3; ++i) {
        int idx = i * 256 + tid;     // 0..767
        int c = idx & 31;
        int x4 = idx >> 5;           // 0..23
        f32x4 v = *(const f32x4*)(src + (size_t)c * HWD + x4 * 4);
#pragma unroll
        for (int k = 0; k < 4; ++k)
            dst[(x4 * 4 + k) * 32 + c] = f2bf(v[k]);
    }
}

// Fused sample + GEMM. Block = 512 threads = 16 vertices x 32 channels.
// Each thread gathers its vertex/channel 4x4x4 window from voxT (channel-last:
// 32 lanes of a vertex read one 64B line per voxel, 100% utilization),
// does the separable x->y->z contraction to 27 taps, writes a bf16 row chunk
// into the LDS A-tile. After the barrier, waves 0/1 run the 16x1024 @ 1024x32
// MFMA GEMM (n-tile = wave id) and write out with bias.
__global__ __launch_bounds__(512) void fused_kernel(const unsigned short* __restrict__ voxT,
                                                    const float* __restrict__ verts,
                                                    const unsigned short* __restrict__ Wp,
                                                    const float* __restrict__ bias,
                                                    float* __restrict__ out) {
    __shared__ unsigned short At[16 * AST];
    int tid = threadIdx.x;
    int vl = tid >> 5;               // 0..15
    int c = tid & 31;
    int vg = (int)blockIdx.x * 16 + vl;   // 3750*16 = 60000 exactly

    const float* vp = verts + (size_t)vg * 3;
    float vx = vp[0], vy = vp[1], vz = vp[2];
    const float sc = 2.0f / 95.0f;
    int wsx, wsy, wsz;
    float wx[3][4], wy[3][4], wz[3][4];
    axis_setup(vx, sc, wsx, wx);  // x -> D axis (innermost spatial)
    axis_setup(vy, sc, wsy, wy);  // y -> W axis
    axis_setup(vz, sc, wsz, wz);  // z -> H axis
    int bb = (vg >= NV) ? 1 : 0;
    const unsigned short* vb = voxT + (size_t)bb * HWD * 32 + c;

    float f[27];
#pragma unroll
    for (int k = 0; k < 27; ++k) f[k] = 0.0f;

#pragma unroll
    for (int tz = 0; tz < 4; ++tz) {
        float rx[4][3];
#pragma unroll
        for (int ty = 0; ty < 4; ++ty) {
            const unsigned short* row =
                vb + (((size_t)(wsz + tz) * 96 + (size_t)(wsy + ty)) * 96 + wsx) * 32;
            float b0 = bf2f(row[0]);
            float b1 = bf2f(row[32]);
            float b2 = bf2f(row[64]);
            float b3 = bf2f(row[96]);
#pragma unroll
            for (int a = 0; a < 3; ++a)
                rx[ty][a] = b0 * wx[a][0] + b1 * wx[a][1] + b2 * wx[a][2] + b3 * wx[a][3];
        }
        float ry[3][3];
#pragma unroll
        for (int b = 0; b < 3; ++b)
#pragma unroll
            for (int a = 0; a < 3; ++a)
                ry[b][a] = rx[0][a] * wy[b][0] + rx[1][a] * wy[b][1] +
                           rx[2][a] * wy[b][2] + rx[3][a] * wy[b][3];
#pragma unroll
        for (int g = 0; g < 3; ++g)
#pragma unroll
            for (int b = 0; b < 3; ++b)
#pragma unroll
                for (int a = 0; a < 3; ++a)
                    f[9 * a + 3 * b + g] += wz[g][tz] * ry[b][a];
    }

    unsigned int pk[16];
#pragma unroll
    for (int i = 0; i < 16; ++i) {
        float lo = (2 * i < 27) ? f[2 * i] : 0.0f;
        float hi = (2 * i + 1 < 27) ? f[2 * i + 1] : 0.0f;
        pk[i] = (unsigned int)f2bf(lo) | ((unsigned int)f2bf(hi) << 16);
    }
    // A-tile row vl, cols [c*32, c*32+32): K index = c*32 + kk (27 real + 5 zero)
    uint4v* dst = (uint4v*)&At[vl * AST + c * 32];
    uint4v s0 = {pk[0], pk[1], pk[2], pk[3]};
    uint4v s1 = {pk[4], pk[5], pk[6], pk[7]};
    uint4v s2 = {pk[8], pk[9], pk[10], pk[11]};
    uint4v s3 = {pk[12], pk[13], pk[14], pk[15]};
    dst[0] = s0; dst[1] = s1; dst[2] = s2; dst[3] = s3;

    __syncthreads();

    int wv = tid >> 6;               // wave id 0..7; waves 0,1 do the GEMM
    if (wv < 2) {
        int lane = tid & 63;
        int mrow = lane & 15, quad = lane >> 4;
        const bf16x8* wp = (const bf16x8*)Wp;
        const unsigned short* arow = &At[mrow * AST + quad * 8];
        f32x4 acc = {0.f, 0.f, 0.f, 0.f};
#pragma unroll 8
        for (int s = 0; s < 32; ++s) {
            bf16x8 a = *(const bf16x8*)(arow + s * 32);
            bf16x8 b = wp[(s * 2 + wv) * 64 + lane];
            acc = __builtin_amdgcn_mfma_f32_16x16x32_bf16(a, b, acc, 0, 0, 0);
        }
        float bs = bias[wv * 16 + mrow];
#pragma unroll
        for (int r = 0; r < 4; ++r) {
            int v = (int)blockIdx.x * 16 + quad * 4 + r;
            out[(size_t)v * 32 + wv * 16 + mrow] = acc[r] + bs;
        }
    }
}

extern "C" void kernel_launch(void* const* d_in, const int* in_sizes, int n_in,
                              void* d_out, int out_size, void* d_ws, size_t ws_size,
                              hipStream_t stream) {
    const float* vox = (const float*)d_in[0];
    const float* verts = (const float*)d_in[1];
    const float* cw = (const float*)d_in[2];
    const float* cb = (const float*)d_in[3];
    float* out = (float*)d_out;

    // ws layout: Wp (64 KB) | voxT bf16 (2*HWD*32*2 = 113.25 MB). Total ~113.4 MB.
    unsigned short* Wp = (unsigned short*)d_ws;
    unsigned short* voxT = (unsigned short*)((char*)d_ws + 65536);

    hipLaunchKernelGGL(prep_kernel, dim3(128), dim3(256), 0, stream, cw, Wp);
    hipLaunchKernelGGL(transpose_kernel, dim3(18432), dim3(256), 0, stream, vox, voxT);
    hipLaunchKernelGGL(fused_kernel, dim3(3750), dim3(512), 0, stream,
                       voxT, verts, Wp, cb, out);
}